// Round 7
// baseline (320.595 us; speedup 1.0000x reference)
//
#include <hip/hip_runtime.h>
#include <math.h>

#define N_ING 100000
#define N_TASTE 50000
#define D 128
#define NEG_SLOPE 0.2f

typedef float nt4 __attribute__((ext_vector_type(4)));  // native vec for nontemporal builtin

// ---------------------------------------------------------------------------
// prep: v_dst[k] = sum_j W_taste[k][j] * att_dst[j]; c_dst = b_taste . att_dst
// (h_dst is only ever consumed through the dot with att_dst, so the whole
//  x_taste @ W_taste GEMM collapses to one matvec against v_dst.)
// ---------------------------------------------------------------------------
__global__ __launch_bounds__(128) void k_prep(const float* __restrict__ W_taste,
                                              const float* __restrict__ b_taste,
                                              const float* __restrict__ att_dst,
                                              float* __restrict__ v_dst,
                                              float* __restrict__ c_dst) {
  __shared__ float red[128];
  const int t = threadIdx.x;
  float acc = 0.f;
  const float* row = W_taste + t * D;
  for (int d = 0; d < D; d += 4) {
    float4 w = *(const float4*)(row + d);
    float4 a = *(const float4*)(att_dst + d);
    acc += w.x * a.x + w.y * a.y + w.z * a.z + w.w * a.w;
  }
  v_dst[t] = acc;
  red[t] = b_taste[t] * att_dst[t];
  __syncthreads();
  for (int off = 64; off > 0; off >>= 1) {
    if (t < off) red[t] += red[t + off];
    __syncthreads();
  }
  if (t == 0) *c_dst = red[0];
}

// ---------------------------------------------------------------------------
// GEMM: H = x_ing @ W_ing + b_ing, fused a_src[row] = H[row,:] . att_src,
// fused passthrough copy x_ing -> pass_out (first output slot, nontemporal:
// written once, never re-read -> don't evict H's L2/L3 working set).
// 128x128 block tile, 256 threads, 8x8 per-thread, K chunked by 32.
// Wl layout [g=col/8][kk][8] stride 260 floats -> 2-way bank access (free).
// Xt transposed [kk][row] stride 132 -> 16B-aligned, reads broadcast.
// ---------------------------------------------------------------------------
__global__ __launch_bounds__(256) void k_gemm(const float* __restrict__ X,
                                              const float* __restrict__ W,
                                              const float* __restrict__ bias,
                                              const float* __restrict__ att,
                                              float* __restrict__ H,
                                              float* __restrict__ a_src,
                                              float* __restrict__ pass_out) {
  __shared__ __align__(16) float Xt[32 * 132];
  __shared__ __align__(16) float Wl[16 * 260];
  const int tid = threadIdx.x;
  const int tr = tid >> 4, tc = tid & 15;
  const int r0 = tr * 8, c0 = tc * 8;
  const int brow = blockIdx.x * 128;

  float acc[8][8];
#pragma unroll
  for (int i = 0; i < 8; ++i)
#pragma unroll
    for (int j = 0; j < 8; ++j) acc[i][j] = 0.f;

  for (int k0 = 0; k0 < D; k0 += 32) {
    // stage W chunk [32 k][128 j]
#pragma unroll
    for (int p = 0; p < 4; ++p) {
      int f = p * 256 + tid;          // 0..1023 float4s
      int kk = f >> 5;                // 0..31
      int j4 = f & 31;                // float4 col index
      float4 w4 = *(const float4*)(W + (size_t)(k0 + kk) * D + j4 * 4);
      int g = j4 >> 1;
      int u0 = (j4 & 1) * 4;
      *(float4*)&Wl[g * 260 + kk * 8 + u0] = w4;
    }
    // stage Xt transposed chunk (+ fused passthrough store of x_ing)
#pragma unroll
    for (int p = 0; p < 4; ++p) {
      int f = p * 256 + tid;
      int r = f >> 3;
      int kq = (f & 7) * 4;
      int row = brow + r;
      float4 x4 = make_float4(0.f, 0.f, 0.f, 0.f);
      if (row < N_ING) {
        x4 = *(const float4*)(X + (size_t)row * D + k0 + kq);
        if (pass_out)
          __builtin_nontemporal_store(*(const nt4*)&x4,
              (nt4*)(pass_out + (size_t)row * D + k0 + kq));
      }
      Xt[(kq + 0) * 132 + r] = x4.x;
      Xt[(kq + 1) * 132 + r] = x4.y;
      Xt[(kq + 2) * 132 + r] = x4.z;
      Xt[(kq + 3) * 132 + r] = x4.w;
    }
    __syncthreads();
#pragma unroll 4
    for (int kk = 0; kk < 32; ++kk) {
      float xa[8], wb[8];
      *(float4*)&xa[0] = *(const float4*)&Xt[kk * 132 + r0];
      *(float4*)&xa[4] = *(const float4*)&Xt[kk * 132 + r0 + 4];
      *(float4*)&wb[0] = *(const float4*)&Wl[tc * 260 + kk * 8];
      *(float4*)&wb[4] = *(const float4*)&Wl[tc * 260 + kk * 8 + 4];
#pragma unroll
      for (int i = 0; i < 8; ++i)
#pragma unroll
        for (int j = 0; j < 8; ++j) acc[i][j] = fmaf(xa[i], wb[j], acc[i][j]);
    }
    __syncthreads();
  }

  // epilogue: bias add, store H, fused a_src reduce over the 16 tc lanes
  float bj[8], av[8];
  *(float4*)&bj[0] = *(const float4*)(bias + c0);
  *(float4*)&bj[4] = *(const float4*)(bias + c0 + 4);
  *(float4*)&av[0] = *(const float4*)(att + c0);
  *(float4*)&av[4] = *(const float4*)(att + c0 + 4);
#pragma unroll
  for (int i = 0; i < 8; ++i) {
    int row = brow + r0 + i;
    if (row < N_ING) {
      float o[8];
      float part = 0.f;
#pragma unroll
      for (int j = 0; j < 8; ++j) {
        o[j] = acc[i][j] + bj[j];
        part += o[j] * av[j];
      }
      *(float4*)(H + (size_t)row * D + c0) = *(float4*)&o[0];
      *(float4*)(H + (size_t)row * D + c0 + 4) = *(float4*)&o[4];
      part += __shfl_xor(part, 1);
      part += __shfl_xor(part, 2);
      part += __shfl_xor(part, 4);
      part += __shfl_xor(part, 8);
      if (tc == 0) a_src[row] = part;
    }
  }
}

// ---------------------------------------------------------------------------
// CSR build: histogram -> scan (3 kernels) -> scatter
// ---------------------------------------------------------------------------
__global__ __launch_bounds__(256) void k_hist(const int* __restrict__ dst,
                                              int* __restrict__ count, int E) {
  int e = blockIdx.x * 256 + threadIdx.x;
  if (e < E) atomicAdd(&count[dst[e]], 1);
}

__global__ __launch_bounds__(256) void k_scan1(const int* __restrict__ count,
                                               int* __restrict__ excl,
                                               int* __restrict__ bsum, int n) {
  __shared__ int tmp[256];
  const int tid = threadIdx.x;
  const int i = blockIdx.x * 256 + tid;
  int v = (i < n) ? count[i] : 0;
  tmp[tid] = v;
  __syncthreads();
  for (int off = 1; off < 256; off <<= 1) {
    int a = tmp[tid];
    int b = (tid >= off) ? tmp[tid - off] : 0;
    __syncthreads();
    tmp[tid] = a + b;
    __syncthreads();
  }
  if (i < n) excl[i] = tmp[tid] - v;
  if (tid == 255) bsum[blockIdx.x] = tmp[255];
}

__global__ __launch_bounds__(256) void k_scan2(int* __restrict__ bsum, int nb) {
  __shared__ int tmp[256];
  const int tid = threadIdx.x;
  int v = (tid < nb) ? bsum[tid] : 0;
  tmp[tid] = v;
  __syncthreads();
  for (int off = 1; off < 256; off <<= 1) {
    int a = tmp[tid];
    int b = (tid >= off) ? tmp[tid - off] : 0;
    __syncthreads();
    tmp[tid] = a + b;
    __syncthreads();
  }
  if (tid < nb) bsum[tid] = tmp[tid] - v;  // exclusive
}

__global__ __launch_bounds__(256) void k_scan3(const int* __restrict__ excl,
                                               const int* __restrict__ bsum,
                                               int* __restrict__ offsets,
                                               int* __restrict__ cursor,
                                               int n, int E) {
  const int i = blockIdx.x * 256 + threadIdx.x;
  if (i < n) {
    int o = excl[i] + bsum[blockIdx.x];
    offsets[i] = o;
    cursor[i] = o;
  }
  if (i == 0) offsets[n] = E;
}

// Runs AFTER k_gemm: scatters the src id and the pre-gathered logit
// contribution a_src[src[e]] PACKED as one int2 (8B single scatter instead of
// two 4B scatters). Moves the dependent a_src gather out of the
// latency-critical k_agg into this throughput-bound pass (a_src is a 400 KB
// L2-resident table; E-way parallelism hides all latency).
__global__ __launch_bounds__(256) void k_scatter(const int* __restrict__ src,
                                                 const int* __restrict__ dst,
                                                 const float* __restrict__ a_src,
                                                 int* __restrict__ cursor,
                                                 int2* __restrict__ csr_pack,
                                                 int E) {
  int e = blockIdx.x * 256 + threadIdx.x;
  if (e < E) {
    int s = src[e];
    float a = a_src[s];
    int pos = atomicAdd(&cursor[dst[e]], 1);
    csr_pack[pos] = make_int2(s, __float_as_int(a));
  }
}

// ---------------------------------------------------------------------------
// Per-node fused kernel: one wave per taste node.
//   a_dst[n] = x_taste[n].v_dst + c   (x_taste row reused for the residual)
//   segment softmax (leaky_relu logits), weighted aggregation of H rows,
//   normalize, relu, +x_taste residual.
// Fast path cnt<=64 (covers Poisson(12) degrees): one 8B csr_pack load per
// lane issued before the a_dst matvec (whose shuffle-reduce hides the
// latency); accumulate loop broadcasts (s, ev) via uniform-index shuffles
// (register-only), unrolled x4 with 4 independent accumulators.
// ---------------------------------------------------------------------------
__global__ __launch_bounds__(256) void k_agg(const int* __restrict__ offsets,
                                             const int2* __restrict__ csr_pack,
                                             const float* __restrict__ v_dst,
                                             const float* __restrict__ c_dst,
                                             const float* __restrict__ H,
                                             const float* __restrict__ x_taste,
                                             float* __restrict__ out_taste) {
  const int wid = threadIdx.x >> 6, lane = threadIdx.x & 63;
  const int n = blockIdx.x * 4 + wid;
  const int d = lane * 2;

  const int o0 = offsets[n], o1 = offsets[n + 1];
  const int cnt = o1 - o0;
  const bool fast = (cnt <= 64);

  // issue the packed gather early (single 8B load)
  int2 pk = make_int2(0, 0);
  if (fast && lane < cnt) pk = csr_pack[o0 + lane];
  const int s_l = pk.x;
  const float a_s = __int_as_float(pk.y);

  // residual row (reused) + fused a_dst matvec — overlaps the gather latency
  const float2 xt2 = *(const float2*)(x_taste + (size_t)n * D + d);
  const float2 v2 = *(const float2*)(v_dst + d);
  float adn = xt2.x * v2.x + xt2.y * v2.y;
#pragma unroll
  for (int off = 1; off < 64; off <<= 1) adn += __shfl_xor(adn, off);
  adn += *c_dst;

  float denom = 0.f;
  float2 acc0 = make_float2(0.f, 0.f);
  float2 acc1 = make_float2(0.f, 0.f);
  float2 acc2 = make_float2(0.f, 0.f);
  float2 acc3 = make_float2(0.f, 0.f);

  if (fast) {
    float al_l = -INFINITY;
    if (lane < cnt) {
      float al = a_s + adn;
      al_l = al >= 0.f ? al : NEG_SLOPE * al;
    }
    float am = al_l;
#pragma unroll
    for (int off = 1; off < 64; off <<= 1) am = fmaxf(am, __shfl_xor(am, off));
    float ev_l = (lane < cnt) ? __expf(al_l - am) : 0.f;
    float es = ev_l;
#pragma unroll
    for (int off = 1; off < 64; off <<= 1) es += __shfl_xor(es, off);
    denom = es;
    int e = 0;
    for (; e + 4 <= cnt; e += 4) {
      int s0 = __shfl(s_l, e);            // uniform index -> readlane/SGPR
      int s1 = __shfl(s_l, e + 1);
      int s2 = __shfl(s_l, e + 2);
      int s3 = __shfl(s_l, e + 3);
      float ev0 = __shfl(ev_l, e);
      float ev1 = __shfl(ev_l, e + 1);
      float ev2 = __shfl(ev_l, e + 2);
      float ev3 = __shfl(ev_l, e + 3);
      const float2 h0 = *(const float2*)(H + (size_t)s0 * D + d);
      const float2 h1 = *(const float2*)(H + (size_t)s1 * D + d);
      const float2 h2 = *(const float2*)(H + (size_t)s2 * D + d);
      const float2 h3 = *(const float2*)(H + (size_t)s3 * D + d);
      acc0.x = fmaf(ev0, h0.x, acc0.x);
      acc0.y = fmaf(ev0, h0.y, acc0.y);
      acc1.x = fmaf(ev1, h1.x, acc1.x);
      acc1.y = fmaf(ev1, h1.y, acc1.y);
      acc2.x = fmaf(ev2, h2.x, acc2.x);
      acc2.y = fmaf(ev2, h2.y, acc2.y);
      acc3.x = fmaf(ev3, h3.x, acc3.x);
      acc3.y = fmaf(ev3, h3.y, acc3.y);
    }
    for (; e < cnt; ++e) {
      int s0 = __shfl(s_l, e);
      float ev0 = __shfl(ev_l, e);
      const float2 h0 = *(const float2*)(H + (size_t)s0 * D + d);
      acc0.x = fmaf(ev0, h0.x, acc0.x);
      acc0.y = fmaf(ev0, h0.y, acc0.y);
    }
  } else {
    // generic tiled path (unreachable for Poisson(12), kept for safety)
    float am = -INFINITY;
    for (int i = o0 + lane; i < o1; i += 64) {
      float al = __int_as_float(csr_pack[i].y) + adn;
      al = al >= 0.f ? al : NEG_SLOPE * al;
      am = fmaxf(am, al);
    }
#pragma unroll
    for (int off = 1; off < 64; off <<= 1) am = fmaxf(am, __shfl_xor(am, off));
    for (int base = 0; base < cnt; base += 64) {
      int m = min(64, cnt - base);
      int s_t = 0;
      float ev_t = 0.f;
      if (lane < m) {
        int2 p = csr_pack[o0 + base + lane];
        s_t = p.x;
        float al = __int_as_float(p.y) + adn;
        al = al >= 0.f ? al : NEG_SLOPE * al;
        ev_t = __expf(al - am);
      }
      float es = ev_t;
#pragma unroll
      for (int off = 1; off < 64; off <<= 1) es += __shfl_xor(es, off);
      denom += es;
      int e = 0;
      for (; e + 2 <= m; e += 2) {
        int s0 = __shfl(s_t, e);
        int s1 = __shfl(s_t, e + 1);
        float ev0 = __shfl(ev_t, e);
        float ev1 = __shfl(ev_t, e + 1);
        const float2 h0 = *(const float2*)(H + (size_t)s0 * D + d);
        const float2 h1 = *(const float2*)(H + (size_t)s1 * D + d);
        acc0.x = fmaf(ev0, h0.x, acc0.x);
        acc0.y = fmaf(ev0, h0.y, acc0.y);
        acc1.x = fmaf(ev1, h1.x, acc1.x);
        acc1.y = fmaf(ev1, h1.y, acc1.y);
      }
      if (e < m) {
        int s0 = __shfl(s_t, e);
        float ev0 = __shfl(ev_t, e);
        const float2 h0 = *(const float2*)(H + (size_t)s0 * D + d);
        acc0.x = fmaf(ev0, h0.x, acc0.x);
        acc0.y = fmaf(ev0, h0.y, acc0.y);
      }
    }
  }

  const float inv = 1.f / (denom + 1e-16f);
  float2 r;
  r.x = fmaxf((acc0.x + acc1.x + acc2.x + acc3.x) * inv, 0.f) + xt2.x;
  r.y = fmaxf((acc0.y + acc1.y + acc2.y + acc3.y) * inv, 0.f) + xt2.y;
  *(float2*)(out_taste + (size_t)n * D + d) = r;
}

// ---------------------------------------------------------------------------
extern "C" void kernel_launch(void* const* d_in, const int* in_sizes, int n_in,
                              void* d_out, int out_size, void* d_ws, size_t ws_size,
                              hipStream_t stream) {
  const float* x_ing   = (const float*)d_in[0];
  const float* x_taste = (const float*)d_in[1];
  const int*   src     = (const int*)d_in[2];
  const int*   dst     = (const int*)d_in[3];
  const float* W_ing   = (const float*)d_in[4];
  const float* b_ing   = (const float*)d_in[5];
  const float* W_taste = (const float*)d_in[6];
  const float* b_taste = (const float*)d_in[7];
  const float* att_src = (const float*)d_in[8];
  const float* att_dst = (const float*)d_in[9];
  // d_in[10..12] (W_k, b_k, q) are dead: single edge type -> softmax over one
  // scalar -> beta == 1.0 bit-exactly, so the tanh/W_k GEMM never matters.
  const int E = in_sizes[2];

  float* out_ing   = (float*)d_out;                       // [N_ING, D]
  float* out_taste = (float*)d_out + (size_t)N_ING * D;   // [N_TASTE, D]

  size_t off = 0;
  auto alloc = [&](size_t bytes) -> void* {
    void* p = (char*)d_ws + off;
    off = (off + bytes + 255) & ~(size_t)255;
    return p;
  };
  float* a_src    = (float*)alloc((size_t)N_ING * 4);
  float* v_dst    = (float*)alloc(D * 4);
  float* c_dst    = (float*)alloc(4);
  int* count      = (int*)alloc((size_t)N_TASTE * 4);
  int* excl       = (int*)alloc((size_t)N_TASTE * 4);
  int* bsum       = (int*)alloc(256 * 4);
  int* offsets    = (int*)alloc((size_t)(N_TASTE + 1) * 4);
  int* cursor     = (int*)alloc((size_t)N_TASTE * 4);
  int2* csr_pack  = (int2*)alloc((size_t)E * 8);
  float* H_ws     = (float*)alloc((size_t)N_ING * D * 4);  // 51.2 MB, last
  const bool h_in_ws = (off <= ws_size);                   // constant per run

  // If ws is big enough: H lives in scratch and the GEMM writes the x_ing
  // passthrough itself (saves a 51 MB read + a memcpy node). Otherwise stage
  // H in out_ing and restore it with a D2D copy at the end.
  float* H = h_in_ws ? H_ws : out_ing;

  const int nb_node = (N_TASTE + 255) / 256;   // 196 (<=256, k_scan2 1-block)
  const int nb_edge = (E + 255) / 256;

  (void)hipMemsetAsync(count, 0, (size_t)N_TASTE * 4, stream);
  k_prep<<<1, 128, 0, stream>>>(W_taste, b_taste, att_dst, v_dst, c_dst);
  k_hist<<<nb_edge, 256, 0, stream>>>(dst, count, E);
  k_scan1<<<nb_node, 256, 0, stream>>>(count, excl, bsum, N_TASTE);
  k_scan2<<<1, 256, 0, stream>>>(bsum, nb_node);
  k_scan3<<<nb_node, 256, 0, stream>>>(excl, bsum, offsets, cursor, N_TASTE, E);
  k_gemm<<<(N_ING + 127) / 128, 256, 0, stream>>>(x_ing, W_ing, b_ing, att_src,
                                                  H, a_src,
                                                  h_in_ws ? out_ing : nullptr);
  k_scatter<<<nb_edge, 256, 0, stream>>>(src, dst, a_src, cursor, csr_pack, E);
  k_agg<<<N_TASTE / 4, 256, 0, stream>>>(offsets, csr_pack, v_dst, c_dst,
                                         H, x_taste, out_taste);
  if (!h_in_ws) {
    (void)hipMemcpyAsync(d_out, x_ing, (size_t)N_ING * D * 4,
                         hipMemcpyDeviceToDevice, stream);
  }
}

// Round 9
// 318.166 us; speedup vs baseline: 1.0076x; 1.0076x over previous
//
#include <hip/hip_runtime.h>
#include <math.h>

#define N_ING 100000
#define N_TASTE 50000
#define D 128
#define NEG_SLOPE 0.2f

typedef float nt4 __attribute__((ext_vector_type(4)));  // native vec for nontemporal builtin

// ---------------------------------------------------------------------------
// prep: v_dst[k] = sum_j W_taste[k][j] * att_dst[j]; c_dst = b_taste . att_dst
// ---------------------------------------------------------------------------
__global__ __launch_bounds__(128) void k_prep(const float* __restrict__ W_taste,
                                              const float* __restrict__ b_taste,
                                              const float* __restrict__ att_dst,
                                              float* __restrict__ v_dst,
                                              float* __restrict__ c_dst) {
  __shared__ float red[128];
  const int t = threadIdx.x;
  float acc = 0.f;
  const float* row = W_taste + t * D;
  for (int d = 0; d < D; d += 4) {
    float4 w = *(const float4*)(row + d);
    float4 a = *(const float4*)(att_dst + d);
    acc += w.x * a.x + w.y * a.y + w.z * a.z + w.w * a.w;
  }
  v_dst[t] = acc;
  red[t] = b_taste[t] * att_dst[t];
  __syncthreads();
  for (int off = 64; off > 0; off >>= 1) {
    if (t < off) red[t] += red[t + off];
    __syncthreads();
  }
  if (t == 0) *c_dst = red[0];
}

// ---------------------------------------------------------------------------
// GEMM: H = x_ing @ W_ing + b_ing, fused a_src[row] = H[row,:] . att_src,
// fused nontemporal passthrough x_ing -> pass_out.
// ROUND 8/9: 512 threads, per-thread 4x8 tile (32 acc regs, ~60 VGPR total) --
// round-7 counters showed VGPR_Count=64 with an 8x8 tile (64 acc alone):
// compiler spilled the accumulators -> VALUBusy 35%, 73us. This tile fits.
// __launch_bounds__(512,4): 4 waves/EU min -> 128-VGPR cap, no forced spill.
// 128x128 block tile, K chunked by 32. Wl [g][kk][8] stride 260 (2-way bank,
// free); Xt transposed [kk][row] stride 132.
// ---------------------------------------------------------------------------
__global__ __launch_bounds__(512, 4) void k_gemm(const float* __restrict__ X,
                                                 const float* __restrict__ W,
                                                 const float* __restrict__ bias,
                                                 const float* __restrict__ att,
                                                 float* __restrict__ H,
                                                 float* __restrict__ a_src,
                                                 float* __restrict__ pass_out) {
  __shared__ __align__(16) float Xt[32 * 132];
  __shared__ __align__(16) float Wl[16 * 260];
  const int tid = threadIdx.x;
  const int tr = tid >> 4, tc = tid & 15;   // tr 0..31, tc 0..15
  const int r0 = tr * 4, c0 = tc * 8;
  const int brow = blockIdx.x * 128;

  float acc[4][8];
#pragma unroll
  for (int i = 0; i < 4; ++i)
#pragma unroll
    for (int j = 0; j < 8; ++j) acc[i][j] = 0.f;

  for (int k0 = 0; k0 < D; k0 += 32) {
    // stage W chunk [32 kk][128 j] -> Wl
#pragma unroll
    for (int p = 0; p < 2; ++p) {
      int f = p * 512 + tid;          // 0..1023 float4s
      int kk = f >> 5;                // 0..31
      int j4 = f & 31;                // float4 col index
      float4 w4 = *(const float4*)(W + (size_t)(k0 + kk) * D + j4 * 4);
      int g = j4 >> 1;
      int u0 = (j4 & 1) * 4;
      *(float4*)&Wl[g * 260 + kk * 8 + u0] = w4;
    }
    // stage Xt transposed chunk (+ fused nontemporal passthrough of x_ing)
#pragma unroll
    for (int p = 0; p < 2; ++p) {
      int f = p * 512 + tid;
      int r = f >> 3;                 // 0..127
      int kq = (f & 7) * 4;
      int row = brow + r;
      float4 x4 = make_float4(0.f, 0.f, 0.f, 0.f);
      if (row < N_ING) {
        x4 = *(const float4*)(X + (size_t)row * D + k0 + kq);
        if (pass_out)
          __builtin_nontemporal_store(*(const nt4*)&x4,
              (nt4*)(pass_out + (size_t)row * D + k0 + kq));
      }
      Xt[(kq + 0) * 132 + r] = x4.x;
      Xt[(kq + 1) * 132 + r] = x4.y;
      Xt[(kq + 2) * 132 + r] = x4.z;
      Xt[(kq + 3) * 132 + r] = x4.w;
    }
    __syncthreads();
#pragma unroll 4
    for (int kk = 0; kk < 32; ++kk) {
      float xa[4], wb[8];
      *(float4*)&xa[0] = *(const float4*)&Xt[kk * 132 + r0];
      *(float4*)&wb[0] = *(const float4*)&Wl[tc * 260 + kk * 8];
      *(float4*)&wb[4] = *(const float4*)&Wl[tc * 260 + kk * 8 + 4];
#pragma unroll
      for (int i = 0; i < 4; ++i)
#pragma unroll
        for (int j = 0; j < 8; ++j) acc[i][j] = fmaf(xa[i], wb[j], acc[i][j]);
    }
    __syncthreads();
  }

  // epilogue: bias add, store H, fused a_src reduce over the 16 tc lanes
  float bj[8], av[8];
  *(float4*)&bj[0] = *(const float4*)(bias + c0);
  *(float4*)&bj[4] = *(const float4*)(bias + c0 + 4);
  *(float4*)&av[0] = *(const float4*)(att + c0);
  *(float4*)&av[4] = *(const float4*)(att + c0 + 4);
#pragma unroll
  for (int i = 0; i < 4; ++i) {
    int row = brow + r0 + i;
    if (row < N_ING) {
      float o[8];
      float part = 0.f;
#pragma unroll
      for (int j = 0; j < 8; ++j) {
        o[j] = acc[i][j] + bj[j];
        part += o[j] * av[j];
      }
      *(float4*)(H + (size_t)row * D + c0) = *(float4*)&o[0];
      *(float4*)(H + (size_t)row * D + c0 + 4) = *(float4*)&o[4];
      part += __shfl_xor(part, 1);
      part += __shfl_xor(part, 2);
      part += __shfl_xor(part, 4);
      part += __shfl_xor(part, 8);
      if (tc == 0) a_src[row] = part;
    }
  }
}

// ---------------------------------------------------------------------------
// CSR build: histogram -> scan (3 kernels) -> scatter
// ---------------------------------------------------------------------------
__global__ __launch_bounds__(256) void k_hist(const int* __restrict__ dst,
                                              int* __restrict__ count, int E) {
  int e = blockIdx.x * 256 + threadIdx.x;
  if (e < E) atomicAdd(&count[dst[e]], 1);
}

__global__ __launch_bounds__(256) void k_scan1(const int* __restrict__ count,
                                               int* __restrict__ excl,
                                               int* __restrict__ bsum, int n) {
  __shared__ int tmp[256];
  const int tid = threadIdx.x;
  const int i = blockIdx.x * 256 + tid;
  int v = (i < n) ? count[i] : 0;
  tmp[tid] = v;
  __syncthreads();
  for (int off = 1; off < 256; off <<= 1) {
    int a = tmp[tid];
    int b = (tid >= off) ? tmp[tid - off] : 0;
    __syncthreads();
    tmp[tid] = a + b;
    __syncthreads();
  }
  if (i < n) excl[i] = tmp[tid] - v;
  if (tid == 255) bsum[blockIdx.x] = tmp[255];
}

__global__ __launch_bounds__(256) void k_scan2(int* __restrict__ bsum, int nb) {
  __shared__ int tmp[256];
  const int tid = threadIdx.x;
  int v = (tid < nb) ? bsum[tid] : 0;
  tmp[tid] = v;
  __syncthreads();
  for (int off = 1; off < 256; off <<= 1) {
    int a = tmp[tid];
    int b = (tid >= off) ? tmp[tid - off] : 0;
    __syncthreads();
    tmp[tid] = a + b;
    __syncthreads();
  }
  if (tid < nb) bsum[tid] = tmp[tid] - v;  // exclusive
}

__global__ __launch_bounds__(256) void k_scan3(const int* __restrict__ excl,
                                               const int* __restrict__ bsum,
                                               int* __restrict__ offsets,
                                               int* __restrict__ cursor,
                                               int n, int E) {
  const int i = blockIdx.x * 256 + threadIdx.x;
  if (i < n) {
    int o = excl[i] + bsum[blockIdx.x];
    offsets[i] = o;
    cursor[i] = o;
  }
  if (i == 0) offsets[n] = E;
}

// Runs AFTER k_gemm: scatters (src id, a_src[src]) packed as one int2.
__global__ __launch_bounds__(256) void k_scatter(const int* __restrict__ src,
                                                 const int* __restrict__ dst,
                                                 const float* __restrict__ a_src,
                                                 int* __restrict__ cursor,
                                                 int2* __restrict__ csr_pack,
                                                 int E) {
  int e = blockIdx.x * 256 + threadIdx.x;
  if (e < E) {
    int s = src[e];
    float a = a_src[s];
    int pos = atomicAdd(&cursor[dst[e]], 1);
    csr_pack[pos] = make_int2(s, __float_as_int(a));
  }
}

// ---------------------------------------------------------------------------
// Per-node fused kernel: one wave per taste node. a_dst matvec fused;
// segment softmax + weighted aggregation of H rows; relu + residual.
// ---------------------------------------------------------------------------
__global__ __launch_bounds__(256) void k_agg(const int* __restrict__ offsets,
                                             const int2* __restrict__ csr_pack,
                                             const float* __restrict__ v_dst,
                                             const float* __restrict__ c_dst,
                                             const float* __restrict__ H,
                                             const float* __restrict__ x_taste,
                                             float* __restrict__ out_taste) {
  const int wid = threadIdx.x >> 6, lane = threadIdx.x & 63;
  const int n = blockIdx.x * 4 + wid;
  const int d = lane * 2;

  const int o0 = offsets[n], o1 = offsets[n + 1];
  const int cnt = o1 - o0;
  const bool fast = (cnt <= 64);

  // issue the packed gather early (single 8B load)
  int2 pk = make_int2(0, 0);
  if (fast && lane < cnt) pk = csr_pack[o0 + lane];
  const int s_l = pk.x;
  const float a_s = __int_as_float(pk.y);

  // residual row (reused) + fused a_dst matvec — overlaps the gather latency
  const float2 xt2 = *(const float2*)(x_taste + (size_t)n * D + d);
  const float2 v2 = *(const float2*)(v_dst + d);
  float adn = xt2.x * v2.x + xt2.y * v2.y;
#pragma unroll
  for (int off = 1; off < 64; off <<= 1) adn += __shfl_xor(adn, off);
  adn += *c_dst;

  float denom = 0.f;
  float2 acc0 = make_float2(0.f, 0.f);
  float2 acc1 = make_float2(0.f, 0.f);
  float2 acc2 = make_float2(0.f, 0.f);
  float2 acc3 = make_float2(0.f, 0.f);

  if (fast) {
    float al_l = -INFINITY;
    if (lane < cnt) {
      float al = a_s + adn;
      al_l = al >= 0.f ? al : NEG_SLOPE * al;
    }
    float am = al_l;
#pragma unroll
    for (int off = 1; off < 64; off <<= 1) am = fmaxf(am, __shfl_xor(am, off));
    float ev_l = (lane < cnt) ? __expf(al_l - am) : 0.f;
    float es = ev_l;
#pragma unroll
    for (int off = 1; off < 64; off <<= 1) es += __shfl_xor(es, off);
    denom = es;
    int e = 0;
    for (; e + 4 <= cnt; e += 4) {
      int s0 = __shfl(s_l, e);            // uniform index -> readlane/SGPR
      int s1 = __shfl(s_l, e + 1);
      int s2 = __shfl(s_l, e + 2);
      int s3 = __shfl(s_l, e + 3);
      float ev0 = __shfl(ev_l, e);
      float ev1 = __shfl(ev_l, e + 1);
      float ev2 = __shfl(ev_l, e + 2);
      float ev3 = __shfl(ev_l, e + 3);
      const float2 h0 = *(const float2*)(H + (size_t)s0 * D + d);
      const float2 h1 = *(const float2*)(H + (size_t)s1 * D + d);
      const float2 h2 = *(const float2*)(H + (size_t)s2 * D + d);
      const float2 h3 = *(const float2*)(H + (size_t)s3 * D + d);
      acc0.x = fmaf(ev0, h0.x, acc0.x);
      acc0.y = fmaf(ev0, h0.y, acc0.y);
      acc1.x = fmaf(ev1, h1.x, acc1.x);
      acc1.y = fmaf(ev1, h1.y, acc1.y);
      acc2.x = fmaf(ev2, h2.x, acc2.x);
      acc2.y = fmaf(ev2, h2.y, acc2.y);
      acc3.x = fmaf(ev3, h3.x, acc3.x);
      acc3.y = fmaf(ev3, h3.y, acc3.y);
    }
    for (; e < cnt; ++e) {
      int s0 = __shfl(s_l, e);
      float ev0 = __shfl(ev_l, e);
      const float2 h0 = *(const float2*)(H + (size_t)s0 * D + d);
      acc0.x = fmaf(ev0, h0.x, acc0.x);
      acc0.y = fmaf(ev0, h0.y, acc0.y);
    }
  } else {
    // generic tiled path (unreachable for Poisson(12), kept for safety)
    float am = -INFINITY;
    for (int i = o0 + lane; i < o1; i += 64) {
      float al = __int_as_float(csr_pack[i].y) + adn;
      al = al >= 0.f ? al : NEG_SLOPE * al;
      am = fmaxf(am, al);
    }
#pragma unroll
    for (int off = 1; off < 64; off <<= 1) am = fmaxf(am, __shfl_xor(am, off));
    for (int base = 0; base < cnt; base += 64) {
      int m = min(64, cnt - base);
      int s_t = 0;
      float ev_t = 0.f;
      if (lane < m) {
        int2 p = csr_pack[o0 + base + lane];
        s_t = p.x;
        float al = __int_as_float(p.y) + adn;
        al = al >= 0.f ? al : NEG_SLOPE * al;
        ev_t = __expf(al - am);
      }
      float es = ev_t;
#pragma unroll
      for (int off = 1; off < 64; off <<= 1) es += __shfl_xor(es, off);
      denom += es;
      int e = 0;
      for (; e + 2 <= m; e += 2) {
        int s0 = __shfl(s_t, e);
        int s1 = __shfl(s_t, e + 1);
        float ev0 = __shfl(ev_t, e);
        float ev1 = __shfl(ev_t, e + 1);
        const float2 h0 = *(const float2*)(H + (size_t)s0 * D + d);
        const float2 h1 = *(const float2*)(H + (size_t)s1 * D + d);
        acc0.x = fmaf(ev0, h0.x, acc0.x);
        acc0.y = fmaf(ev0, h0.y, acc0.y);
        acc1.x = fmaf(ev1, h1.x, acc1.x);
        acc1.y = fmaf(ev1, h1.y, acc1.y);
      }
      if (e < m) {
        int s0 = __shfl(s_t, e);
        float ev0 = __shfl(ev_t, e);
        const float2 h0 = *(const float2*)(H + (size_t)s0 * D + d);
        acc0.x = fmaf(ev0, h0.x, acc0.x);
        acc0.y = fmaf(ev0, h0.y, acc0.y);
      }
    }
  }

  const float inv = 1.f / (denom + 1e-16f);
  float2 r;
  r.x = fmaxf((acc0.x + acc1.x + acc2.x + acc3.x) * inv, 0.f) + xt2.x;
  r.y = fmaxf((acc0.y + acc1.y + acc2.y + acc3.y) * inv, 0.f) + xt2.y;
  *(float2*)(out_taste + (size_t)n * D + d) = r;
}

// ---------------------------------------------------------------------------
extern "C" void kernel_launch(void* const* d_in, const int* in_sizes, int n_in,
                              void* d_out, int out_size, void* d_ws, size_t ws_size,
                              hipStream_t stream) {
  const float* x_ing   = (const float*)d_in[0];
  const float* x_taste = (const float*)d_in[1];
  const int*   src     = (const int*)d_in[2];
  const int*   dst     = (const int*)d_in[3];
  const float* W_ing   = (const float*)d_in[4];
  const float* b_ing   = (const float*)d_in[5];
  const float* W_taste = (const float*)d_in[6];
  const float* b_taste = (const float*)d_in[7];
  const float* att_src = (const float*)d_in[8];
  const float* att_dst = (const float*)d_in[9];
  // d_in[10..12] (W_k, b_k, q) are dead: single edge type -> softmax over one
  // scalar -> beta == 1.0 bit-exactly, so the tanh/W_k GEMM never matters.
  const int E = in_sizes[2];

  float* out_ing   = (float*)d_out;                       // [N_ING, D]
  float* out_taste = (float*)d_out + (size_t)N_ING * D;   // [N_TASTE, D]

  size_t off = 0;
  auto alloc = [&](size_t bytes) -> void* {
    void* p = (char*)d_ws + off;
    off = (off + bytes + 255) & ~(size_t)255;
    return p;
  };
  float* a_src    = (float*)alloc((size_t)N_ING * 4);
  float* v_dst    = (float*)alloc(D * 4);
  float* c_dst    = (float*)alloc(4);
  int* count      = (int*)alloc((size_t)N_TASTE * 4);
  int* excl       = (int*)alloc((size_t)N_TASTE * 4);
  int* bsum       = (int*)alloc(256 * 4);
  int* offsets    = (int*)alloc((size_t)(N_TASTE + 1) * 4);
  int* cursor     = (int*)alloc((size_t)N_TASTE * 4);
  int2* csr_pack  = (int2*)alloc((size_t)E * 8);
  float* H_ws     = (float*)alloc((size_t)N_ING * D * 4);  // 51.2 MB, last
  const bool h_in_ws = (off <= ws_size);                   // constant per run

  // If ws is big enough: H lives in scratch and the GEMM writes the x_ing
  // passthrough itself (saves a 51 MB read + a memcpy node). Otherwise stage
  // H in out_ing and restore it with a D2D copy at the end.
  float* H = h_in_ws ? H_ws : out_ing;

  const int nb_node = (N_TASTE + 255) / 256;   // 196 (<=256, k_scan2 1-block)
  const int nb_edge = (E + 255) / 256;

  (void)hipMemsetAsync(count, 0, (size_t)N_TASTE * 4, stream);
  k_prep<<<1, 128, 0, stream>>>(W_taste, b_taste, att_dst, v_dst, c_dst);
  k_hist<<<nb_edge, 256, 0, stream>>>(dst, count, E);
  k_scan1<<<nb_node, 256, 0, stream>>>(count, excl, bsum, N_TASTE);
  k_scan2<<<1, 256, 0, stream>>>(bsum, nb_node);
  k_scan3<<<nb_node, 256, 0, stream>>>(excl, bsum, offsets, cursor, N_TASTE, E);
  k_gemm<<<(N_ING + 127) / 128, 512, 0, stream>>>(x_ing, W_ing, b_ing, att_src,
                                                  H, a_src,
                                                  h_in_ws ? out_ing : nullptr);
  k_scatter<<<nb_edge, 256, 0, stream>>>(src, dst, a_src, cursor, csr_pack, E);
  k_agg<<<N_TASTE / 4, 256, 0, stream>>>(offsets, csr_pack, v_dst, c_dst,
                                         H, x_taste, out_taste);
  if (!h_in_ws) {
    (void)hipMemcpyAsync(d_out, x_ing, (size_t)N_ING * D * 4,
                         hipMemcpyDeviceToDevice, stream);
  }
}

// Round 10
// 317.712 us; speedup vs baseline: 1.0091x; 1.0014x over previous
//
#include <hip/hip_runtime.h>
#include <math.h>

#define N_ING 100000
#define N_TASTE 50000
#define D 128
#define NEG_SLOPE 0.2f

typedef float nt4 __attribute__((ext_vector_type(4)));  // native vec for nontemporal builtin

// ---------------------------------------------------------------------------
// prep: v_dst[k] = sum_j W_taste[k][j] * att_dst[j]; c_dst = b_taste . att_dst
// ---------------------------------------------------------------------------
__global__ __launch_bounds__(128) void k_prep(const float* __restrict__ W_taste,
                                              const float* __restrict__ b_taste,
                                              const float* __restrict__ att_dst,
                                              float* __restrict__ v_dst,
                                              float* __restrict__ c_dst) {
  __shared__ float red[128];
  const int t = threadIdx.x;
  float acc = 0.f;
  const float* row = W_taste + t * D;
  for (int d = 0; d < D; d += 4) {
    float4 w = *(const float4*)(row + d);
    float4 a = *(const float4*)(att_dst + d);
    acc += w.x * a.x + w.y * a.y + w.z * a.z + w.w * a.w;
  }
  v_dst[t] = acc;
  red[t] = b_taste[t] * att_dst[t];
  __syncthreads();
  for (int off = 64; off > 0; off >>= 1) {
    if (t < off) red[t] += red[t + off];
    __syncthreads();
  }
  if (t == 0) *c_dst = red[0];
}

// ---------------------------------------------------------------------------
// GEMM: H = x_ing @ W_ing + b_ing, fused a_src[row] = H[row,:] . att_src.
// ROUND 10: r7 vs r9 showed identical 72.5us across different reg configs ->
// bottleneck is the CORRELATED stall: NT passthrough store inside the
// barrier-synced staging loop forces vmcnt(0) (store drain to HBM, ~900cy)
// before every s_barrier, 4x per block, for all waves at once. Fix: move the
// passthrough copy to the EPILOGUE (after last barrier; X re-read is L2/L3
// hot; store drain overlaps across blocks). Also 8x8 tile @256 thr,
// __launch_bounds__(256,4) (cap 128 VGPR, ~100 used, no spill): LDS read
// traffic drops 1.5 -> 1.0 B/FMA.
// Xt transposed [kk][row] stride 132: xa reads 4 distinct addrs/wave
// (16-way broadcast), conflict-free. Wl [g][kk][8] stride 260: 2-way alias
// (free per m136).
// ---------------------------------------------------------------------------
__global__ __launch_bounds__(256, 4) void k_gemm(const float* __restrict__ X,
                                                 const float* __restrict__ W,
                                                 const float* __restrict__ bias,
                                                 const float* __restrict__ att,
                                                 float* __restrict__ H,
                                                 float* __restrict__ a_src,
                                                 float* __restrict__ pass_out) {
  __shared__ __align__(16) float Xt[32 * 132];
  __shared__ __align__(16) float Wl[16 * 260];
  const int tid = threadIdx.x;
  const int tr = tid >> 4, tc = tid & 15;   // tr 0..15, tc 0..15
  const int r0 = tr * 8, c0 = tc * 8;
  const int brow = blockIdx.x * 128;

  float acc[8][8];
#pragma unroll
  for (int i = 0; i < 8; ++i)
#pragma unroll
    for (int j = 0; j < 8; ++j) acc[i][j] = 0.f;

  for (int k0 = 0; k0 < D; k0 += 32) {
    // stage W chunk [32 kk][128 j] -> Wl (1024 float4s / 256 thr = 4 iters)
#pragma unroll
    for (int p = 0; p < 4; ++p) {
      int f = p * 256 + tid;
      int kk = f >> 5;                // 0..31
      int j4 = f & 31;                // float4 col index
      float4 w4 = *(const float4*)(W + (size_t)(k0 + kk) * D + j4 * 4);
      *(float4*)&Wl[(j4 >> 1) * 260 + kk * 8 + (j4 & 1) * 4] = w4;
    }
    // stage Xt transposed chunk (no passthrough store here anymore!)
#pragma unroll
    for (int p = 0; p < 4; ++p) {
      int f = p * 256 + tid;
      int r = f >> 3;                 // 0..127
      int kq = (f & 7) * 4;
      int row = brow + r;
      float4 x4 = make_float4(0.f, 0.f, 0.f, 0.f);
      if (row < N_ING) x4 = *(const float4*)(X + (size_t)row * D + k0 + kq);
      Xt[(kq + 0) * 132 + r] = x4.x;
      Xt[(kq + 1) * 132 + r] = x4.y;
      Xt[(kq + 2) * 132 + r] = x4.z;
      Xt[(kq + 3) * 132 + r] = x4.w;
    }
    __syncthreads();
#pragma unroll 4
    for (int kk = 0; kk < 32; ++kk) {
      float xa[8], wb[8];
      *(float4*)&xa[0] = *(const float4*)&Xt[kk * 132 + r0];
      *(float4*)&xa[4] = *(const float4*)&Xt[kk * 132 + r0 + 4];
      *(float4*)&wb[0] = *(const float4*)&Wl[tc * 260 + kk * 8];
      *(float4*)&wb[4] = *(const float4*)&Wl[tc * 260 + kk * 8 + 4];
#pragma unroll
      for (int i = 0; i < 8; ++i)
#pragma unroll
        for (int j = 0; j < 8; ++j) acc[i][j] = fmaf(xa[i], wb[j], acc[i][j]);
    }
    __syncthreads();
  }

  // epilogue: bias add, store H, fused a_src reduce over the 16 tc lanes
  float bj[8], av[8];
  *(float4*)&bj[0] = *(const float4*)(bias + c0);
  *(float4*)&bj[4] = *(const float4*)(bias + c0 + 4);
  *(float4*)&av[0] = *(const float4*)(att + c0);
  *(float4*)&av[4] = *(const float4*)(att + c0 + 4);
#pragma unroll
  for (int i = 0; i < 8; ++i) {
    int row = brow + r0 + i;
    if (row < N_ING) {
      float o[8];
      float part = 0.f;
#pragma unroll
      for (int j = 0; j < 8; ++j) {
        o[j] = acc[i][j] + bj[j];
        part += o[j] * av[j];
      }
      *(float4*)(H + (size_t)row * D + c0) = *(float4*)&o[0];
      *(float4*)(H + (size_t)row * D + c0 + 4) = *(float4*)&o[4];
      part += __shfl_xor(part, 1);
      part += __shfl_xor(part, 2);
      part += __shfl_xor(part, 4);
      part += __shfl_xor(part, 8);
      if (tc == 0) a_src[row] = part;
    }
  }

  // passthrough copy x_ing -> pass_out, AFTER the last barrier: X tile is
  // L2/L3-hot from staging; NT stores drain at kernel end (overlapped across
  // blocks), never blocking a barrier. 4096 float4s / 256 thr = 16 each.
  if (pass_out) {
#pragma unroll 4
    for (int p = 0; p < 16; ++p) {
      int f = p * 256 + tid;          // 0..4095
      int r = f >> 5;                 // 32 float4 per row
      int q = (f & 31) * 4;
      int row = brow + r;
      if (row < N_ING) {
        float4 x4 = *(const float4*)(X + (size_t)row * D + q);
        __builtin_nontemporal_store(*(const nt4*)&x4,
            (nt4*)(pass_out + (size_t)row * D + q));
      }
    }
  }
}

// ---------------------------------------------------------------------------
// CSR build: histogram -> scan (3 kernels) -> scatter
// ---------------------------------------------------------------------------
__global__ __launch_bounds__(256) void k_hist(const int* __restrict__ dst,
                                              int* __restrict__ count, int E) {
  int e = blockIdx.x * 256 + threadIdx.x;
  if (e < E) atomicAdd(&count[dst[e]], 1);
}

__global__ __launch_bounds__(256) void k_scan1(const int* __restrict__ count,
                                               int* __restrict__ excl,
                                               int* __restrict__ bsum, int n) {
  __shared__ int tmp[256];
  const int tid = threadIdx.x;
  const int i = blockIdx.x * 256 + tid;
  int v = (i < n) ? count[i] : 0;
  tmp[tid] = v;
  __syncthreads();
  for (int off = 1; off < 256; off <<= 1) {
    int a = tmp[tid];
    int b = (tid >= off) ? tmp[tid - off] : 0;
    __syncthreads();
    tmp[tid] = a + b;
    __syncthreads();
  }
  if (i < n) excl[i] = tmp[tid] - v;
  if (tid == 255) bsum[blockIdx.x] = tmp[255];
}

__global__ __launch_bounds__(256) void k_scan2(int* __restrict__ bsum, int nb) {
  __shared__ int tmp[256];
  const int tid = threadIdx.x;
  int v = (tid < nb) ? bsum[tid] : 0;
  tmp[tid] = v;
  __syncthreads();
  for (int off = 1; off < 256; off <<= 1) {
    int a = tmp[tid];
    int b = (tid >= off) ? tmp[tid - off] : 0;
    __syncthreads();
    tmp[tid] = a + b;
    __syncthreads();
  }
  if (tid < nb) bsum[tid] = tmp[tid] - v;  // exclusive
}

__global__ __launch_bounds__(256) void k_scan3(const int* __restrict__ excl,
                                               const int* __restrict__ bsum,
                                               int* __restrict__ offsets,
                                               int* __restrict__ cursor,
                                               int n, int E) {
  const int i = blockIdx.x * 256 + threadIdx.x;
  if (i < n) {
    int o = excl[i] + bsum[blockIdx.x];
    offsets[i] = o;
    cursor[i] = o;
  }
  if (i == 0) offsets[n] = E;
}

// Runs AFTER k_gemm: scatters (src id, a_src[src]) packed as one int2.
__global__ __launch_bounds__(256) void k_scatter(const int* __restrict__ src,
                                                 const int* __restrict__ dst,
                                                 const float* __restrict__ a_src,
                                                 int* __restrict__ cursor,
                                                 int2* __restrict__ csr_pack,
                                                 int E) {
  int e = blockIdx.x * 256 + threadIdx.x;
  if (e < E) {
    int s = src[e];
    float a = a_src[s];
    int pos = atomicAdd(&cursor[dst[e]], 1);
    csr_pack[pos] = make_int2(s, __float_as_int(a));
  }
}

// ---------------------------------------------------------------------------
// Per-node fused kernel: one wave per taste node. a_dst matvec fused;
// segment softmax + weighted aggregation of H rows; relu + residual.
// ---------------------------------------------------------------------------
__global__ __launch_bounds__(256) void k_agg(const int* __restrict__ offsets,
                                             const int2* __restrict__ csr_pack,
                                             const float* __restrict__ v_dst,
                                             const float* __restrict__ c_dst,
                                             const float* __restrict__ H,
                                             const float* __restrict__ x_taste,
                                             float* __restrict__ out_taste) {
  const int wid = threadIdx.x >> 6, lane = threadIdx.x & 63;
  const int n = blockIdx.x * 4 + wid;
  const int d = lane * 2;

  const int o0 = offsets[n], o1 = offsets[n + 1];
  const int cnt = o1 - o0;
  const bool fast = (cnt <= 64);

  // issue the packed gather early (single 8B load)
  int2 pk = make_int2(0, 0);
  if (fast && lane < cnt) pk = csr_pack[o0 + lane];
  const int s_l = pk.x;
  const float a_s = __int_as_float(pk.y);

  // residual row (reused) + fused a_dst matvec — overlaps the gather latency
  const float2 xt2 = *(const float2*)(x_taste + (size_t)n * D + d);
  const float2 v2 = *(const float2*)(v_dst + d);
  float adn = xt2.x * v2.x + xt2.y * v2.y;
#pragma unroll
  for (int off = 1; off < 64; off <<= 1) adn += __shfl_xor(adn, off);
  adn += *c_dst;

  float denom = 0.f;
  float2 acc0 = make_float2(0.f, 0.f);
  float2 acc1 = make_float2(0.f, 0.f);
  float2 acc2 = make_float2(0.f, 0.f);
  float2 acc3 = make_float2(0.f, 0.f);

  if (fast) {
    float al_l = -INFINITY;
    if (lane < cnt) {
      float al = a_s + adn;
      al_l = al >= 0.f ? al : NEG_SLOPE * al;
    }
    float am = al_l;
#pragma unroll
    for (int off = 1; off < 64; off <<= 1) am = fmaxf(am, __shfl_xor(am, off));
    float ev_l = (lane < cnt) ? __expf(al_l - am) : 0.f;
    float es = ev_l;
#pragma unroll
    for (int off = 1; off < 64; off <<= 1) es += __shfl_xor(es, off);
    denom = es;
    int e = 0;
    for (; e + 4 <= cnt; e += 4) {
      int s0 = __shfl(s_l, e);            // uniform index -> readlane/SGPR
      int s1 = __shfl(s_l, e + 1);
      int s2 = __shfl(s_l, e + 2);
      int s3 = __shfl(s_l, e + 3);
      float ev0 = __shfl(ev_l, e);
      float ev1 = __shfl(ev_l, e + 1);
      float ev2 = __shfl(ev_l, e + 2);
      float ev3 = __shfl(ev_l, e + 3);
      const float2 h0 = *(const float2*)(H + (size_t)s0 * D + d);
      const float2 h1 = *(const float2*)(H + (size_t)s1 * D + d);
      const float2 h2 = *(const float2*)(H + (size_t)s2 * D + d);
      const float2 h3 = *(const float2*)(H + (size_t)s3 * D + d);
      acc0.x = fmaf(ev0, h0.x, acc0.x);
      acc0.y = fmaf(ev0, h0.y, acc0.y);
      acc1.x = fmaf(ev1, h1.x, acc1.x);
      acc1.y = fmaf(ev1, h1.y, acc1.y);
      acc2.x = fmaf(ev2, h2.x, acc2.x);
      acc2.y = fmaf(ev2, h2.y, acc2.y);
      acc3.x = fmaf(ev3, h3.x, acc3.x);
      acc3.y = fmaf(ev3, h3.y, acc3.y);
    }
    for (; e < cnt; ++e) {
      int s0 = __shfl(s_l, e);
      float ev0 = __shfl(ev_l, e);
      const float2 h0 = *(const float2*)(H + (size_t)s0 * D + d);
      acc0.x = fmaf(ev0, h0.x, acc0.x);
      acc0.y = fmaf(ev0, h0.y, acc0.y);
    }
  } else {
    // generic tiled path (unreachable for Poisson(12), kept for safety)
    float am = -INFINITY;
    for (int i = o0 + lane; i < o1; i += 64) {
      float al = __int_as_float(csr_pack[i].y) + adn;
      al = al >= 0.f ? al : NEG_SLOPE * al;
      am = fmaxf(am, al);
    }
#pragma unroll
    for (int off = 1; off < 64; off <<= 1) am = fmaxf(am, __shfl_xor(am, off));
    for (int base = 0; base < cnt; base += 64) {
      int m = min(64, cnt - base);
      int s_t = 0;
      float ev_t = 0.f;
      if (lane < m) {
        int2 p = csr_pack[o0 + base + lane];
        s_t = p.x;
        float al = __int_as_float(p.y) + adn;
        al = al >= 0.f ? al : NEG_SLOPE * al;
        ev_t = __expf(al - am);
      }
      float es = ev_t;
#pragma unroll
      for (int off = 1; off < 64; off <<= 1) es += __shfl_xor(es, off);
      denom += es;
      int e = 0;
      for (; e + 2 <= m; e += 2) {
        int s0 = __shfl(s_t, e);
        int s1 = __shfl(s_t, e + 1);
        float ev0 = __shfl(ev_t, e);
        float ev1 = __shfl(ev_t, e + 1);
        const float2 h0 = *(const float2*)(H + (size_t)s0 * D + d);
        const float2 h1 = *(const float2*)(H + (size_t)s1 * D + d);
        acc0.x = fmaf(ev0, h0.x, acc0.x);
        acc0.y = fmaf(ev0, h0.y, acc0.y);
        acc1.x = fmaf(ev1, h1.x, acc1.x);
        acc1.y = fmaf(ev1, h1.y, acc1.y);
      }
      if (e < m) {
        int s0 = __shfl(s_t, e);
        float ev0 = __shfl(ev_t, e);
        const float2 h0 = *(const float2*)(H + (size_t)s0 * D + d);
        acc0.x = fmaf(ev0, h0.x, acc0.x);
        acc0.y = fmaf(ev0, h0.y, acc0.y);
      }
    }
  }

  const float inv = 1.f / (denom + 1e-16f);
  float2 r;
  r.x = fmaxf((acc0.x + acc1.x + acc2.x + acc3.x) * inv, 0.f) + xt2.x;
  r.y = fmaxf((acc0.y + acc1.y + acc2.y + acc3.y) * inv, 0.f) + xt2.y;
  *(float2*)(out_taste + (size_t)n * D + d) = r;
}

// ---------------------------------------------------------------------------
extern "C" void kernel_launch(void* const* d_in, const int* in_sizes, int n_in,
                              void* d_out, int out_size, void* d_ws, size_t ws_size,
                              hipStream_t stream) {
  const float* x_ing   = (const float*)d_in[0];
  const float* x_taste = (const float*)d_in[1];
  const int*   src     = (const int*)d_in[2];
  const int*   dst     = (const int*)d_in[3];
  const float* W_ing   = (const float*)d_in[4];
  const float* b_ing   = (const float*)d_in[5];
  const float* W_taste = (const float*)d_in[6];
  const float* b_taste = (const float*)d_in[7];
  const float* att_src = (const float*)d_in[8];
  const float* att_dst = (const float*)d_in[9];
  // d_in[10..12] (W_k, b_k, q) are dead: single edge type -> softmax over one
  // scalar -> beta == 1.0 bit-exactly, so the tanh/W_k GEMM never matters.
  const int E = in_sizes[2];

  float* out_ing   = (float*)d_out;                       // [N_ING, D]
  float* out_taste = (float*)d_out + (size_t)N_ING * D;   // [N_TASTE, D]

  size_t off = 0;
  auto alloc = [&](size_t bytes) -> void* {
    void* p = (char*)d_ws + off;
    off = (off + bytes + 255) & ~(size_t)255;
    return p;
  };
  float* a_src    = (float*)alloc((size_t)N_ING * 4);
  float* v_dst    = (float*)alloc(D * 4);
  float* c_dst    = (float*)alloc(4);
  int* count      = (int*)alloc((size_t)N_TASTE * 4);
  int* excl       = (int*)alloc((size_t)N_TASTE * 4);
  int* bsum       = (int*)alloc(256 * 4);
  int* offsets    = (int*)alloc((size_t)(N_TASTE + 1) * 4);
  int* cursor     = (int*)alloc((size_t)N_TASTE * 4);
  int2* csr_pack  = (int2*)alloc((size_t)E * 8);
  float* H_ws     = (float*)alloc((size_t)N_ING * D * 4);  // 51.2 MB, last
  const bool h_in_ws = (off <= ws_size);                   // constant per run

  // If ws is big enough: H lives in scratch and the GEMM writes the x_ing
  // passthrough itself (saves a 51 MB read + a memcpy node). Otherwise stage
  // H in out_ing and restore it with a D2D copy at the end.
  float* H = h_in_ws ? H_ws : out_ing;

  const int nb_node = (N_TASTE + 255) / 256;   // 196 (<=256, k_scan2 1-block)
  const int nb_edge = (E + 255) / 256;

  (void)hipMemsetAsync(count, 0, (size_t)N_TASTE * 4, stream);
  k_prep<<<1, 128, 0, stream>>>(W_taste, b_taste, att_dst, v_dst, c_dst);
  k_hist<<<nb_edge, 256, 0, stream>>>(dst, count, E);
  k_scan1<<<nb_node, 256, 0, stream>>>(count, excl, bsum, N_TASTE);
  k_scan2<<<1, 256, 0, stream>>>(bsum, nb_node);
  k_scan3<<<nb_node, 256, 0, stream>>>(excl, bsum, offsets, cursor, N_TASTE, E);
  k_gemm<<<(N_ING + 127) / 128, 256, 0, stream>>>(x_ing, W_ing, b_ing, att_src,
                                                  H, a_src,
                                                  h_in_ws ? out_ing : nullptr);
  k_scatter<<<nb_edge, 256, 0, stream>>>(src, dst, a_src, cursor, csr_pack, E);
  k_agg<<<N_TASTE / 4, 256, 0, stream>>>(offsets, csr_pack, v_dst, c_dst,
                                         H, x_taste, out_taste);
  if (!h_in_ws) {
    (void)hipMemcpyAsync(d_out, x_ing, (size_t)N_ING * D * 4,
                         hipMemcpyDeviceToDevice, stream);
  }
}